// Round 6
// baseline (1909.172 us; speedup 1.0000x reference)
//
#include <hip/hip_runtime.h>
#include <cstdint>
#include <cstddef>

#define B_   32
#define T_   128
#define H_   1024
#define V_   32000
#define NBLK 256
#define NTHR 512
#define JB   4        // hidden columns per block -> 12 W_hh rows
#define BH_  (B_*H_)  // 32768 floats per h buffer
#define RST  49       // red row stride (odd -> lane*17 mod 32 permutation, conflict-free)

// LDS layout (floats):
//   Wl  [12][1024]   12288  (W_hh tile, resident across all 128 steps)
//   red [512][49]    25088  (k-split partial spill)
//   ghl [12][32]       384  (reduced gh tile)
#define LDS_WL_OFF   0
#define LDS_RED_OFF  (12*1024)
#define LDS_GHL_OFF  (12*1024 + 512*RST)
#define LDS_FLOATS   (12*1024 + 512*RST + 12*32)

__global__ __launch_bounds__(NTHR) void gru_persist(
    const float* __restrict__ Whh,   // (3072,1024)
    const float* __restrict__ bhh,   // (3072)
    const float* __restrict__ Wih,   // (3072,32000)
    const float* __restrict__ bih,   // (3072)
    const int*   __restrict__ xs,    // (B,T)
    float*       __restrict__ hbase, // T_ x (B,H) step buffers (address-rotated)
    int*         __restrict__ flags, // (NBLK*32) zeroed before launch
    float*       __restrict__ outp,  // (B,T,H)
    float*       __restrict__ hidout)// (B,H)
{
    extern __shared__ float lds[];
    float* Wl  = lds + LDS_WL_OFF;
    float* red = lds + LDS_RED_OFF;
    float* ghl = lds + LDS_GHL_OFF;

    const int tid = threadIdx.x;
    const int bid = (int)blockIdx.x;
    const int j0  = bid * JB;

    // ---- stage W_hh tile into LDS ONCE (12 rows x 1024, float4 coalesced) ----
    #pragma unroll
    for (int i = 0; i < 6; ++i) {
        const int idx = i * NTHR + tid;   // float4 index 0..3071
        const int r   = idx >> 8;         // row 0..11
        const int kv  = idx & 255;
        const int g   = r >> 2, jj = r & 3;
        ((float4*)(Wl + r * H_))[kv] =
            ((const float4*)(Whh + (size_t)(g*H_ + j0 + jj) * H_))[kv];
    }

    const int gjj = tid & 3;          // gate-phase column-within-block
    const int gb  = tid >> 2;         // gate-phase batch
    const int kq  = tid & 63;         // GEMM k-slice lane
    const int bq4 = (tid >> 6) & 3;   // GEMM batch quad-of-4
    const int h16 = tid >> 8;         // GEMM batch half (0/1)
    const int b0  = h16 * 16 + bq4 * 4;  // first of this thread's 4 batches
    const int cph = (bid >> 6) & 3;   // k-group phase: start at own flag's group

    // reduce-thread constants
    float rbias = 0.f;
    if (tid < 96) {
        const int r = tid >> 3;
        rbias = bhh[(r >> 2) * H_ + j0 + (r & 3)];
    }

    // gate-phase constants + gather prefetch for t=0
    const size_t gr0 = (size_t)(0*H_ + j0 + gjj) * V_;
    const size_t gr1 = (size_t)(1*H_ + j0 + gjj) * V_;
    const size_t gr2 = (size_t)(2*H_ + j0 + gjj) * V_;
    float bih0 = 0.f, bih1 = 0.f, bih2 = 0.f;
    float nxg0 = 0.f, nxg1 = 0.f, nxg2 = 0.f;
    if (tid < 128) {
        bih0 = bih[0*H_ + j0 + gjj];
        bih1 = bih[1*H_ + j0 + gjj];
        bih2 = bih[2*H_ + j0 + gjj];
        const int tok = xs[gb * T_];
        nxg0 = Wih[gr0 + tok];
        nxg1 = Wih[gr1 + tok];
        nxg2 = Wih[gr2 + tok];
    }

    __syncthreads();   // W tile ready

    for (int t = 0; t < T_; ++t) {
        // address-rotated h buffers: read hstep[t-1], write hstep[t].
        // Fresh read addresses each step -> no stale L2 copies -> plain loads ok.
        const float* __restrict__ hcur = hbase + (size_t)(t > 0 ? t - 1 : 0) * BH_;
        float*       __restrict__ hnxt = hbase + (size_t)t * BH_;

        const float xg0 = nxg0 + bih0;
        const float xg1 = nxg1 + bih1;
        const float xg2 = nxg2 + bih2;
        float hold = 0.f;
        if (tid < 128 && t > 0) hold = hcur[(size_t)gb * H_ + j0 + gjj];

        // issue NEXT step's scattered W_ih gather; latency hides under GEMM
        if (tid < 128 && t + 1 < T_) {
            const int tok = xs[gb * T_ + t + 1];
            nxg0 = Wih[gr0 + tok];
            nxg1 = Wih[gr1 + tok];
            nxg2 = Wih[gr2 + tok];
        }

        // ---- GEMM: gh(12 x 32) = W(12x1024) . h(32x1024)^T ----
        // Dataflow-gated: k-chunk [k, k+4) is produced by block j = k>>2.
        // Each lane polls exactly the producer flag it needs, then loads.
        float acc[12][4];
        #pragma unroll
        for (int r = 0; r < 12; ++r)
            #pragma unroll
            for (int bb = 0; bb < 4; ++bb) acc[r][bb] = 0.f;

        if (t > 0) {
            #pragma unroll
            for (int c = 0; c < 4; ++c) {
                const int cc = (c + cph) & 3;
                const int k  = kq * 4 + cc * 256;
                {   // wait until producer block (cc*64+kq) completed step t-1
                    const int j = cc * 64 + kq;
                    int v;
                    do {
                        v = __hip_atomic_load(&flags[j * 32], __ATOMIC_RELAXED,
                                              __HIP_MEMORY_SCOPE_AGENT);
                    } while (v < t);
                }
                asm volatile("" ::: "memory");  // loads below must not be hoisted

                float4 h4[4];
                #pragma unroll
                for (int bb = 0; bb < 4; ++bb)
                    h4[bb] = *(const float4*)(hcur + (size_t)(b0 + bb) * H_ + k);
                float4 w4[12];
                #pragma unroll
                for (int r = 0; r < 12; ++r)
                    w4[r] = *(const float4*)(Wl + r * H_ + k);
                #pragma unroll
                for (int r = 0; r < 12; ++r) {
                    #pragma unroll
                    for (int bb = 0; bb < 4; ++bb) {
                        acc[r][bb] += w4[r].x * h4[bb].x;
                        acc[r][bb] += w4[r].y * h4[bb].y;
                        acc[r][bb] += w4[r].z * h4[bb].z;
                        acc[r][bb] += w4[r].w * h4[bb].w;
                    }
                }
            }
        }

        // ---- spill partials: red[tid][r*4 .. +4] (odd stride -> conflict-free) ----
        #pragma unroll
        for (int r = 0; r < 12; ++r) {
            const float4 v = make_float4(acc[r][0], acc[r][1], acc[r][2], acc[r][3]);
            *(float4*)(red + (size_t)tid * RST + r * 4) = v;
        }
        __syncthreads();

        // ---- reduce across 64 k-slices (96 threads; bg*9 rotation -> 2/bank) ----
        if (tid < 96) {
            const int r    = tid >> 3;      // 0..11
            const int bg   = tid & 7;       // batch-group of 4
            const int base = (bg >> 2) * 256 + (bg & 3) * 64;  // partial row base
            float4 s = make_float4(0.f, 0.f, 0.f, 0.f);
            #pragma unroll 8
            for (int qq = 0; qq < 64; ++qq) {
                const int q = (qq + bg * 9) & 63;
                const float4 v = *(const float4*)(red + (size_t)(base + q) * RST + r * 4);
                s.x += v.x; s.y += v.y; s.z += v.z; s.w += v.w;
            }
            s.x += rbias; s.y += rbias; s.z += rbias; s.w += rbias;
            *(float4*)(ghl + r * 32 + bg * 4) = s;   // ghl[r][b]
        }
        __syncthreads();

        // ---- gate math + writes (threads 0..127) ----
        if (tid < 128) {
            const float hr = ghl[(0*4 + gjj) * 32 + gb];
            const float hz = ghl[(1*4 + gjj) * 32 + gb];
            const float hn = ghl[(2*4 + gjj) * 32 + gb];
            const float rg = 1.f / (1.f + __expf(-(xg0 + hr)));
            const float zg = 1.f / (1.f + __expf(-(xg1 + hz)));
            const float tn = xg2 + rg * hn;
            const float e  = __expf(-2.f * fabsf(tn));
            const float m  = (1.f - e) / (1.f + e);
            const float ng = copysignf(m, tn);          // tanh, inf-safe
            const float hnew = (1.f - zg) * ng + zg * hold;

            // device-coherent write-through (sc1); relaxed -> no wbl2/inv emitted
            __hip_atomic_store(&hnxt[(size_t)gb * H_ + j0 + gjj], hnew,
                               __ATOMIC_RELAXED, __HIP_MEMORY_SCOPE_AGENT);
            outp[((size_t)gb * T_ + t) * H_ + j0 + gjj] = hnew;
            if (t == T_ - 1) hidout[(size_t)gb * H_ + j0 + gjj] = hnew;
        }

        // ---- publish: all waves' h stores drained (vmcnt(0) in syncthreads),
        //      then tid0 raises this block's monotone step counter. No global
        //      barrier: consumers poll per-chunk inside their GEMM loops.
        __syncthreads();
        if (tid == 0) {
            __hip_atomic_store(&flags[bid * 32], t + 1,
                               __ATOMIC_RELAXED, __HIP_MEMORY_SCOPE_AGENT);
        }
    }
}

extern "C" void kernel_launch(void* const* d_in, const int* in_sizes, int n_in,
                              void* d_out, int out_size, void* d_ws, size_t ws_size,
                              hipStream_t stream) {
    const int*   xs  = (const int*)  d_in[0];
    const float* Wih = (const float*)d_in[1];
    const float* Whh = (const float*)d_in[2];
    const float* bih = (const float*)d_in[3];
    const float* bhh = (const float*)d_in[4];

    float* outp = (float*)d_out;
    float* hid  = outp + (size_t)B_ * T_ * H_;

    float* hbase = (float*)d_ws;                       // T_ * 128KB = 16 MB
    int*   flags = (int*)(hbase + (size_t)T_ * BH_);

    // zero the barrier flags every launch (graph-replay deterministic)
    (void)hipMemsetAsync(flags, 0, (size_t)NBLK * 32 * sizeof(int), stream);

    const size_t LDSB = (size_t)LDS_FLOATS * sizeof(float);   // 151040 B
    (void)hipFuncSetAttribute((const void*)gru_persist,
                              hipFuncAttributeMaxDynamicSharedMemorySize,
                              (int)LDSB);

    gru_persist<<<NBLK, NTHR, LDSB, stream>>>(
        Whh, bhh, Wih, bih, xs, hbase, flags, outp, hid);

    (void)in_sizes; (void)n_in; (void)out_size; (void)ws_size;
}

// Round 7
// 1740.639 us; speedup vs baseline: 1.0968x; 1.0968x over previous
//
#include <hip/hip_runtime.h>
#include <cstdint>
#include <cstddef>

#define B_   32
#define T_   128
#define H_   1024
#define V_   32000
#define NBLK 64
#define NTHR 768       // 12 waves: (gate 0..2) x (batch-half 0..1) x (k-half 0..1)
#define JB   16        // columns per block -> 48 W rows = 3 gates x 16-row MFMA strip
#define BH_  (B_*H_)   // 32768 elements per h buffer

typedef short  short8  __attribute__((ext_vector_type(8)));
typedef short  short4v __attribute__((ext_vector_type(4)));
typedef float  f32x4   __attribute__((ext_vector_type(4)));

// LDS byte layout:
//   hhi [32 b][2048 B]  65536   (bf16 hi of h, XOR-swizzled 16B slots)
//   hlo [32 b][2048 B]  65536   (bf16 lo)
//   ghp f32 [2 kh][48 row][33]  12672  (k-half partial gh, stride-33 anti-conflict)
#define LDS_HHI   0
#define LDS_HLO   65536
#define LDS_GHP   131072
#define LDS_BYTES (131072 + 2*48*33*4)   // 143744

__device__ __forceinline__ unsigned short bf16_rtn(float f) {
    unsigned u = __float_as_uint(f);
    u += 0x7FFFu + ((u >> 16) & 1u);
    return (unsigned short)(u >> 16);
}

__global__ __launch_bounds__(NTHR) void gru_persist(
    const float* __restrict__ Whh,   // (3072,1024)
    const float* __restrict__ bhh,   // (3072)
    const float* __restrict__ Wih,   // (3072,32000)
    const float* __restrict__ bih,   // (3072)
    const int*   __restrict__ xs,    // (B,T)
    unsigned*    __restrict__ hpk,   // T_ x (B,H) packed (hi16|lo16) h buffers
    int*         __restrict__ flags, // (NBLK*32) zeroed before launch
    float*       __restrict__ outp,  // (B,T,H)
    float*       __restrict__ hidout)// (B,H)
{
    extern __shared__ char lds[];
    char*  hhi = lds + LDS_HHI;
    char*  hlo = lds + LDS_HLO;
    float* ghp = (float*)(lds + LDS_GHP);

    const int tid  = threadIdx.x;
    const int bid  = (int)blockIdx.x;
    const int j0   = bid * JB;
    const int lane = tid & 63;
    const int wid  = tid >> 6;         // 0..11
    const int g    = wid >> 2;         // gate 0..2
    const int bh   = (wid >> 1) & 1;   // batch half
    const int kh   = wid & 1;          // k half

    // ---- W A-fragments -> registers, once. wA[kkl]: lane holds
    // W[g*H + j0 + (lane&15)][kk*32 + (lane>>4)*8 + j], kk = kh*16+kkl ----
    short8 wAhi[16], wAlo[16];
    {
        const int   arow = lane & 15;
        const int   q    = lane >> 4;
        const float* wr  = Whh + (size_t)(g * H_ + j0 + arow) * H_;
        #pragma unroll
        for (int kkl = 0; kkl < 16; ++kkl) {
            const int kk = kh * 16 + kkl;
            const float4 w0 = *(const float4*)(wr + kk * 32 + q * 8);
            const float4 w1 = *(const float4*)(wr + kk * 32 + q * 8 + 4);
            const float wv[8] = {w0.x, w0.y, w0.z, w0.w, w1.x, w1.y, w1.z, w1.w};
            short8 hi8, lo8;
            #pragma unroll
            for (int j = 0; j < 8; ++j) {
                const unsigned short h = bf16_rtn(wv[j]);
                const float hf = __uint_as_float((unsigned)h << 16);
                hi8[j] = (short)h;
                lo8[j] = (short)bf16_rtn(wv[j] - hf);
            }
            wAhi[kkl] = hi8;
            wAlo[kkl] = lo8;
        }
    }

    // ---- B-frag LDS addressing constants (lane&15 = batch row within half) ----
    const int brow  = bh * 16 + (lane & 15);
    const int bq    = lane >> 4;
    const int bbase = brow * 2048;
    const int bhash = (lane & 7) << 4;   // == (brow&7)<<4

    // ---- gate-thread constants (tid<512): jj = tid&15 col, b = tid>>4 batch ----
    const int jj = tid & 15;
    const int b  = tid >> 4;
    float bih0 = 0.f, bih1 = 0.f, bih2 = 0.f;
    float bhh0 = 0.f, bhh1 = 0.f, bhh2 = 0.f;
    float nxg0 = 0.f, nxg1 = 0.f, nxg2 = 0.f;
    float hold = 0.f;
    size_t gr0 = 0, gr1 = 0, gr2 = 0;
    if (tid < 512) {
        gr0 = (size_t)(0 * H_ + j0 + jj) * V_;
        gr1 = (size_t)(1 * H_ + j0 + jj) * V_;
        gr2 = (size_t)(2 * H_ + j0 + jj) * V_;
        bih0 = bih[0 * H_ + j0 + jj];
        bih1 = bih[1 * H_ + j0 + jj];
        bih2 = bih[2 * H_ + j0 + jj];
        bhh0 = bhh[0 * H_ + j0 + jj];
        bhh1 = bhh[1 * H_ + j0 + jj];
        bhh2 = bhh[2 * H_ + j0 + jj];
        const int tok = xs[b * T_];      // t=0 gather prefetch
        nxg0 = Wih[gr0 + tok];
        nxg1 = Wih[gr1 + tok];
        nxg2 = Wih[gr2 + tok];
    }

    __syncthreads();

    #pragma unroll 1
    for (int t = 0; t < T_; ++t) {
        const unsigned* hp_prev = hpk + (size_t)(t - 1) * BH_;  // valid t>0
        unsigned*       hp_cur  = hpk + (size_t)t * BH_;

        // consume this step's gather; issue next step's (full step of cover)
        const float cg0 = nxg0, cg1 = nxg1, cg2 = nxg2;
        if (tid < 512 && t + 1 < T_) {
            const int tok = xs[b * T_ + t + 1];
            nxg0 = Wih[gr0 + tok];
            nxg1 = Wih[gr1 + tok];
            nxg2 = Wih[gr2 + tok];
        }

        if (t > 0) {
            // ---- rendezvous: 1 thread per producer flag (64 flags) ----
            if (tid < 64) {
                const int* fp = flags + tid * 32;
                int v;
                do {
                    v = __hip_atomic_load(fp, __ATOMIC_RELAXED,
                                          __HIP_MEMORY_SCOPE_AGENT);
                } while (v < t);
            }
            __syncthreads();

            // ---- stage packed h -> swizzled split-bf16 LDS ----
            // chunk c (uint4 = 4 packed cols): b = c>>8, k0 = (c&255)*4
            uint4 st[11];
            #pragma unroll
            for (int i = 0; i < 11; ++i) {
                const int c = tid + i * NTHR;
                if (c < 8192) st[i] = ((const uint4*)hp_prev)[c];
            }
            #pragma unroll
            for (int i = 0; i < 11; ++i) {
                const int c = tid + i * NTHR;
                if (c < 8192) {
                    const int bb  = c >> 8;
                    const int k0  = (c & 255) * 4;
                    const int off = bb * 2048 + ((k0 * 2) ^ ((bb & 7) << 4));
                    short4v hi4, lo4;
                    hi4[0] = (short)(st[i].x >> 16); lo4[0] = (short)(st[i].x & 0xFFFFu);
                    hi4[1] = (short)(st[i].y >> 16); lo4[1] = (short)(st[i].y & 0xFFFFu);
                    hi4[2] = (short)(st[i].z >> 16); lo4[2] = (short)(st[i].z & 0xFFFFu);
                    hi4[3] = (short)(st[i].w >> 16); lo4[3] = (short)(st[i].w & 0xFFFFu);
                    *(short4v*)(hhi + off) = hi4;
                    *(short4v*)(hlo + off) = lo4;
                }
            }
            __syncthreads();
        }

        // ---- MFMA: 3 passes split-bf16, 16 k-steps per wave (k-half) ----
        f32x4 ahh = {0.f, 0.f, 0.f, 0.f};
        f32x4 ahl = {0.f, 0.f, 0.f, 0.f};
        f32x4 alh = {0.f, 0.f, 0.f, 0.f};
        if (t > 0) {
            #pragma unroll
            for (int kkl = 0; kkl < 16; ++kkl) {
                const int kk  = kh * 16 + kkl;
                const int off = (kk * 64 + bq * 16) ^ bhash;
                const short8 bhi8 = *(const short8*)(hhi + bbase + off);
                const short8 blo8 = *(const short8*)(hlo + bbase + off);
                ahh = __builtin_amdgcn_mfma_f32_16x16x32_bf16(wAhi[kkl], bhi8, ahh, 0, 0, 0);
                ahl = __builtin_amdgcn_mfma_f32_16x16x32_bf16(wAhi[kkl], blo8, ahl, 0, 0, 0);
                alh = __builtin_amdgcn_mfma_f32_16x16x32_bf16(wAlo[kkl], bhi8, alh, 0, 0, 0);
            }
        }

        // ---- k-half partials -> LDS (C layout: col=lane&15=batch, row=(lane>>4)*4+r) ----
        {
            const int bcol = bh * 16 + (lane & 15);
            #pragma unroll
            for (int r = 0; r < 4; ++r) {
                const int m = (lane >> 4) * 4 + r;
                ghp[kh * 1584 + (g * 16 + m) * 33 + bcol] = ahh[r] + ahl[r] + alh[r];
            }
        }
        __syncthreads();

        // ---- gate math + publish (threads 0..511) ----
        if (tid < 512) {
            float hr = bhh0, hz = bhh1, hn = bhh2;
            if (t > 0) {
                hr += ghp[(0 * 16 + jj) * 33 + b] + ghp[1584 + (0 * 16 + jj) * 33 + b];
                hz += ghp[(1 * 16 + jj) * 33 + b] + ghp[1584 + (1 * 16 + jj) * 33 + b];
                hn += ghp[(2 * 16 + jj) * 33 + b] + ghp[1584 + (2 * 16 + jj) * 33 + b];
            }
            const float rg = 1.f / (1.f + __expf(-(cg0 + bih0 + hr)));
            const float zg = 1.f / (1.f + __expf(-(cg1 + bih1 + hz)));
            const float tn = cg2 + bih2 + rg * hn;
            const float e  = __expf(-2.f * fabsf(tn));
            const float m  = (1.f - e) / (1.f + e);
            const float ng = copysignf(m, tn);           // tanh, inf-safe
            const float hnew = (1.f - zg) * ng + zg * hold;
            hold = hnew;                                  // h_old stays in-register

            const unsigned short hh = bf16_rtn(hnew);
            const float hf = __uint_as_float((unsigned)hh << 16);
            const unsigned short hl = bf16_rtn(hnew - hf);
            const unsigned pk = ((unsigned)hh << 16) | (unsigned)hl;
            // device-coherent write-through (sc1); relaxed -> no wbl2/inv
            __hip_atomic_store(hp_cur + (size_t)b * H_ + j0 + jj, pk,
                               __ATOMIC_RELAXED, __HIP_MEMORY_SCOPE_AGENT);
            outp[((size_t)b * T_ + t) * H_ + j0 + jj] = hnew;
            if (t == T_ - 1) hidout[(size_t)b * H_ + j0 + jj] = hnew;
        }

        // ---- publish: syncthreads drains all sc1 stores (vmcnt(0)), then flag ----
        __syncthreads();
        if (tid == 0) {
            __hip_atomic_store(&flags[bid * 32], t + 1,
                               __ATOMIC_RELAXED, __HIP_MEMORY_SCOPE_AGENT);
        }
    }
}

extern "C" void kernel_launch(void* const* d_in, const int* in_sizes, int n_in,
                              void* d_out, int out_size, void* d_ws, size_t ws_size,
                              hipStream_t stream) {
    const int*   xs  = (const int*)  d_in[0];
    const float* Wih = (const float*)d_in[1];
    const float* Whh = (const float*)d_in[2];
    const float* bih = (const float*)d_in[3];
    const float* bhh = (const float*)d_in[4];

    float* outp = (float*)d_out;
    float* hid  = outp + (size_t)B_ * T_ * H_;

    unsigned* hpk   = (unsigned*)d_ws;                   // 128 x 128 KB = 16 MB
    int*      flags = (int*)(hpk + (size_t)T_ * BH_);

    // zero the barrier flags every launch (graph-replay deterministic)
    (void)hipMemsetAsync(flags, 0, (size_t)NBLK * 32 * sizeof(int), stream);

    const size_t LDSB = LDS_BYTES;                       // 143744 B
    (void)hipFuncSetAttribute((const void*)gru_persist,
                              hipFuncAttributeMaxDynamicSharedMemorySize,
                              (int)LDSB);

    gru_persist<<<NBLK, NTHR, LDSB, stream>>>(
        Whh, bhh, Wih, bih, xs, hpk, flags, outp, hid);

    (void)in_sizes; (void)n_in; (void)out_size; (void)ws_size;
}